// Round 4
// baseline (428.782 us; speedup 1.0000x reference)
//
#include <hip/hip_runtime.h>
#include <hip/hip_bf16.h>

#define NN 100000
#define NE 800000
#define DIM 96
#define NEG_SLOPE 0.01f
#define SCAN_BLOCKS ((NN + 255) / 256)   // 391

// ---------------- CSR build ----------------

__global__ __launch_bounds__(256) void hist_kernel(const int* __restrict__ src, int* __restrict__ deg) {
    int e = blockIdx.x * 256 + threadIdx.x;
    if (e < NE) atomicAdd(&deg[src[e]], 1);
}

__global__ __launch_bounds__(256) void partial_kernel(const int* __restrict__ deg, int* __restrict__ blocksum) {
    __shared__ int lds[4];
    int idx = blockIdx.x * 256 + threadIdx.x;
    int v = (idx < NN) ? deg[idx] : 0;
    for (int off = 32; off > 0; off >>= 1) v += __shfl_down(v, off);
    int wave = threadIdx.x >> 6;
    int lane = threadIdx.x & 63;
    if (lane == 0) lds[wave] = v;
    __syncthreads();
    if (threadIdx.x == 0) blocksum[blockIdx.x] = lds[0] + lds[1] + lds[2] + lds[3];
}

__global__ __launch_bounds__(512) void scan_partials_kernel(const int* __restrict__ blocksum, int* __restrict__ blockoff) {
    __shared__ int lds[512];
    int i = threadIdx.x;
    int v = (i < SCAN_BLOCKS) ? blocksum[i] : 0;
    lds[i] = v;
    __syncthreads();
    for (int off = 1; off < 512; off <<= 1) {
        int t = (i >= off) ? lds[i - off] : 0;
        __syncthreads();
        lds[i] += t;
        __syncthreads();
    }
    if (i < SCAN_BLOCKS) blockoff[i] = lds[i] - v;
}

__global__ __launch_bounds__(256) void rowptr_kernel(const int* __restrict__ deg, const int* __restrict__ blockoff,
                                                     int* __restrict__ row_ptr, int* __restrict__ cursor) {
    __shared__ int lds[256];
    int i = threadIdx.x;
    int idx = blockIdx.x * 256 + i;
    int v = (idx < NN) ? deg[idx] : 0;
    lds[i] = v;
    __syncthreads();
    for (int off = 1; off < 256; off <<= 1) {
        int t = (i >= off) ? lds[i - off] : 0;
        __syncthreads();
        lds[i] += t;
        __syncthreads();
    }
    if (idx < NN) {
        int r = blockoff[blockIdx.x] + lds[i] - v;
        row_ptr[idx] = r;
        cursor[idx]  = r;
    }
    if (idx == 0) row_ptr[NN] = NE;
}

__global__ __launch_bounds__(256) void fill_kernel(const int* __restrict__ src, const int* __restrict__ dst,
                                                   int* __restrict__ cursor, int2* __restrict__ sd_pairs) {
    int e = blockIdx.x * 256 + threadIdx.x;
    if (e < NE) {
        int s = src[e];
        int pos = atomicAdd(&cursor[s], 1);
        sd_pairs[pos] = make_int2(s, dst[e]);
    }
}

// ---------------- GEMM: C[N,96] = A[N,96] @ W[96,96] ----------------
// block (12,16) = 192 threads; block tile 192 rows x 96 cols; thread tile
// 12 rows x 8 cols (cols strided by 12: c = tx + 12*m).
// LDS: Wt[c][k] (96x100, staged once, b128-over-k reads, 2-way max conflicts)
//      As[k][r]  (16x192 per chunk, b128-over-r reads, broadcast over tx)
// 49.5 KB LDS -> 3 blocks/CU = 9 waves/CU.

__global__ __launch_bounds__(192) void gemm96_kernel(const float* __restrict__ A, const float* __restrict__ W,
                                                     float* __restrict__ C, int n) {
    __shared__ float Wt[96 * 100];   // [c][k], k-stride 100
    __shared__ float As[16 * 192];   // [k][r], r-stride 192

    const int tx = threadIdx.x;      // 0..11
    const int ty = threadIdx.y;      // 0..15
    const int t  = ty * 12 + tx;     // 0..191
    const int row0 = blockIdx.x * 192;

    // stage Wt (transpose): idx -> k fast (clean LDS writes; global served by L2)
    for (int idx = t; idx < 2304; idx += 192) {
        int k = idx % 96, c4 = idx / 96;           // c4 in [0,24)
        float4 v = *(const float4*)(W + k * 96 + c4 * 4);
        Wt[(c4 * 4 + 0) * 100 + k] = v.x;
        Wt[(c4 * 4 + 1) * 100 + k] = v.y;
        Wt[(c4 * 4 + 2) * 100 + k] = v.z;
        Wt[(c4 * 4 + 3) * 100 + k] = v.w;
    }

    float acc[12][8];
#pragma unroll
    for (int i = 0; i < 12; i++)
#pragma unroll
        for (int m = 0; m < 8; m++) acc[i][m] = 0.f;

    const int grow = row0 + t;
    const bool rvalid = grow < n;
    const float* arow = A + (size_t)grow * DIM;

    for (int chunk = 0; chunk < 6; chunk++) {
        const int kc = chunk * 16;
        __syncthreads();   // protect As (prev chunk reads done; also covers Wt stage on chunk 0)
        // stage A chunk transposed: thread t owns global row row0+t, 16 k's
#pragma unroll
        for (int j = 0; j < 4; j++) {
            float4 v = make_float4(0.f, 0.f, 0.f, 0.f);
            if (rvalid) v = *(const float4*)(arow + kc + j * 4);
            As[(j * 4 + 0) * 192 + t] = v.x;
            As[(j * 4 + 1) * 192 + t] = v.y;
            As[(j * 4 + 2) * 192 + t] = v.z;
            As[(j * 4 + 3) * 192 + t] = v.w;
        }
        __syncthreads();

#pragma unroll
        for (int k4 = 0; k4 < 4; k4++) {
            const int k = kc + k4 * 4;             // global k, multiple of 4
            float4 w[8];
#pragma unroll
            for (int m = 0; m < 8; m++) {
                w[m] = *(const float4*)&Wt[(tx + 12 * m) * 100 + k];
            }
#pragma unroll
            for (int dk = 0; dk < 4; dk++) {
                const int kk = k4 * 4 + dk;        // k within chunk
                float4 a0 = *(const float4*)&As[kk * 192 + ty * 12 + 0];
                float4 a1 = *(const float4*)&As[kk * 192 + ty * 12 + 4];
                float4 a2 = *(const float4*)&As[kk * 192 + ty * 12 + 8];
                const float wv[8] = { ((const float*)&w[0])[dk], ((const float*)&w[1])[dk],
                                      ((const float*)&w[2])[dk], ((const float*)&w[3])[dk],
                                      ((const float*)&w[4])[dk], ((const float*)&w[5])[dk],
                                      ((const float*)&w[6])[dk], ((const float*)&w[7])[dk] };
#pragma unroll
                for (int m = 0; m < 8; m++) {
                    acc[0][m]  = fmaf(a0.x, wv[m], acc[0][m]);
                    acc[1][m]  = fmaf(a0.y, wv[m], acc[1][m]);
                    acc[2][m]  = fmaf(a0.z, wv[m], acc[2][m]);
                    acc[3][m]  = fmaf(a0.w, wv[m], acc[3][m]);
                    acc[4][m]  = fmaf(a1.x, wv[m], acc[4][m]);
                    acc[5][m]  = fmaf(a1.y, wv[m], acc[5][m]);
                    acc[6][m]  = fmaf(a1.z, wv[m], acc[6][m]);
                    acc[7][m]  = fmaf(a1.w, wv[m], acc[7][m]);
                    acc[8][m]  = fmaf(a2.x, wv[m], acc[8][m]);
                    acc[9][m]  = fmaf(a2.y, wv[m], acc[9][m]);
                    acc[10][m] = fmaf(a2.z, wv[m], acc[10][m]);
                    acc[11][m] = fmaf(a2.w, wv[m], acc[11][m]);
                }
            }
        }
    }

    // epilogue: scalar stores, rows ty*12+i, cols tx+12m
#pragma unroll
    for (int i = 0; i < 12; i++) {
        int gr = row0 + ty * 12 + i;
        if (gr < n) {
            float* crow = C + (size_t)gr * DIM;
#pragma unroll
            for (int m = 0; m < 8; m++) crow[tx + 12 * m] = acc[i][m];
        }
    }
}

// ---------------- per-node attention dots ----------------

__global__ __launch_bounds__(256) void dots_kernel(const float* __restrict__ h, const float* __restrict__ a,
                                                   float* __restrict__ ssrc, float* __restrict__ sdst) {
    int gid  = blockIdx.x * 256 + threadIdx.x;
    int node = gid >> 6;
    int lane = threadIdx.x & 63;
    if (node >= NN) return;
    const float* hr = h + (size_t)node * DIM;
    float v0 = hr[lane];
    float v1 = (lane < 32) ? hr[64 + lane] : 0.f;
    float a0 = a[lane];
    float a1v = (lane < 32) ? a[64 + lane] : 0.f;
    float b0 = a[96 + lane];
    float b1 = (lane < 32) ? a[160 + lane] : 0.f;
    float ps = v0 * a0 + v1 * a1v;
    float pd = v0 * b0 + v1 * b1;
    for (int off = 32; off > 0; off >>= 1) {
        ps += __shfl_down(ps, off);
        pd += __shfl_down(pd, off);
    }
    if (lane == 0) {
        ssrc[node] = ps;
        sdst[node] = pd;
    }
}

// ---------------- edge weights (edge-parallel, permuted order) ----------------

__global__ __launch_bounds__(256) void edgew_kernel(const int2* __restrict__ sd_pairs,
                                                    const float* __restrict__ ssrc, const float* __restrict__ sdst,
                                                    int2* __restrict__ w_pairs) {
    int p = blockIdx.x * 256 + threadIdx.x;
    if (p >= NE) return;
    int2 sd = sd_pairs[p];
    float s  = ssrc[sd.x] + sdst[sd.y];
    float lr = s > 0.f ? s : NEG_SLOPE * s;
    float w  = __expf(-lr);
    w_pairs[p] = make_int2(sd.y, __float_as_int(w));
}

// ---------------- CSR aggregation ----------------

template <bool RELU>
__global__ __launch_bounds__(256) void agg_kernel(const float* __restrict__ h,
                                                  const int* __restrict__ row_ptr,
                                                  const int2* __restrict__ w_pairs,
                                                  float* __restrict__ out) {
    int gid  = blockIdx.x * 256 + threadIdx.x;
    int node = gid >> 6;
    int lane = threadIdx.x & 63;
    if (node >= NN) return;
    int start = row_ptr[node];
    int end   = row_ptr[node + 1];
    float acc0 = 0.f, acc1 = 0.f, wsum = 0.f;

    int p = start;
    for (; p + 4 <= end; p += 4) {
        int2 q0 = w_pairs[p + 0];
        int2 q1 = w_pairs[p + 1];
        int2 q2 = w_pairs[p + 2];
        int2 q3 = w_pairs[p + 3];
        const float* h0 = h + (size_t)q0.x * DIM;
        const float* h1 = h + (size_t)q1.x * DIM;
        const float* h2 = h + (size_t)q2.x * DIM;
        const float* h3 = h + (size_t)q3.x * DIM;
        float w0 = __int_as_float(q0.y), w1 = __int_as_float(q1.y);
        float w2 = __int_as_float(q2.y), w3 = __int_as_float(q3.y);
        float x0 = h0[lane], x1 = h1[lane], x2 = h2[lane], x3 = h3[lane];
        float y0 = 0.f, y1 = 0.f, y2 = 0.f, y3 = 0.f;
        if (lane < 32) {
            y0 = h0[64 + lane]; y1 = h1[64 + lane]; y2 = h2[64 + lane]; y3 = h3[64 + lane];
        }
        acc0 = fmaf(w0, x0, fmaf(w1, x1, fmaf(w2, x2, fmaf(w3, x3, acc0))));
        acc1 = fmaf(w0, y0, fmaf(w1, y1, fmaf(w2, y2, fmaf(w3, y3, acc1))));
        wsum += (w0 + w1) + (w2 + w3);
    }
    for (; p < end; p++) {
        int2 q = w_pairs[p];
        const float* hr = h + (size_t)q.x * DIM;
        float w = __int_as_float(q.y);
        wsum += w;
        acc0 = fmaf(w, hr[lane], acc0);
        if (lane < 32) acc1 = fmaf(w, hr[64 + lane], acc1);
    }

    float inv = 1.f / wsum;
    float r0 = acc0 * inv;
    float r1 = acc1 * inv;
    if (RELU) {
        r0 = fmaxf(r0, 0.f);
        r1 = fmaxf(r1, 0.f);
    }
    float* orow = out + (size_t)node * DIM;
    orow[lane] = r0;
    if (lane < 32) orow[64 + lane] = r1;
}

// ---------------- launch ----------------

extern "C" void kernel_launch(void* const* d_in, const int* in_sizes, int n_in,
                              void* d_out, int out_size, void* d_ws, size_t ws_size,
                              hipStream_t stream) {
    (void)in_sizes; (void)n_in; (void)out_size; (void)ws_size;
    const int*   edge_index = (const int*)d_in[0];
    const float* x  = (const float*)d_in[1];
    const float* W1 = (const float*)d_in[2];
    const float* a1 = (const float*)d_in[3];
    const float* W2 = (const float*)d_in[4];
    const float* a2 = (const float*)d_in[5];
    float* out = (float*)d_out;

    const int* src = edge_index;
    const int* dst = edge_index + NE;

    char* ws = (char*)d_ws;
    size_t off = 0;
    auto alloc = [&](size_t bytes) -> void* {
        void* p = ws + off;
        off += (bytes + 255) & ~(size_t)255;
        return p;
    };
    float* hA       = (float*)alloc((size_t)NN * DIM * 4);
    float* hB       = (float*)alloc((size_t)NN * DIM * 4);
    float* ssrc     = (float*)alloc((size_t)NN * 4);
    float* sdst     = (float*)alloc((size_t)NN * 4);
    int*   deg      = (int*)alloc((size_t)NN * 4);
    int*   row_ptr  = (int*)alloc((size_t)(NN + 1) * 4);
    int*   cursor   = (int*)alloc((size_t)NN * 4);
    int2*  sd_pairs = (int2*)alloc((size_t)NE * 8);
    int2*  w_pairs  = (int2*)alloc((size_t)NE * 8);
    int*   blocksum = (int*)alloc((size_t)SCAN_BLOCKS * 4);
    int*   blockoff = (int*)alloc((size_t)SCAN_BLOCKS * 4);

    // ---- build CSR ----
    hipMemsetAsync(deg, 0, (size_t)NN * 4, stream);
    hist_kernel<<<(NE + 255) / 256, 256, 0, stream>>>(src, deg);
    partial_kernel<<<SCAN_BLOCKS, 256, 0, stream>>>(deg, blocksum);
    scan_partials_kernel<<<1, 512, 0, stream>>>(blocksum, blockoff);
    rowptr_kernel<<<SCAN_BLOCKS, 256, 0, stream>>>(deg, blockoff, row_ptr, cursor);
    fill_kernel<<<(NE + 255) / 256, 256, 0, stream>>>(src, dst, cursor, sd_pairs);

    dim3 gemm_block(12, 16);
    int gemm_grid   = (NN + 191) / 192;               // 521
    int wave_blocks = ((NN * 64) + 255) / 256;        // 25000
    int edge_blocks = (NE + 255) / 256;               // 3125

    // ---- layer 1 ----
    gemm96_kernel<<<gemm_grid, gemm_block, 0, stream>>>(x, W1, hA, NN);
    dots_kernel<<<wave_blocks, 256, 0, stream>>>(hA, a1, ssrc, sdst);
    edgew_kernel<<<edge_blocks, 256, 0, stream>>>(sd_pairs, ssrc, sdst, w_pairs);
    agg_kernel<false><<<wave_blocks, 256, 0, stream>>>(hA, row_ptr, w_pairs, hB);

    // ---- layer 2 ----
    gemm96_kernel<<<gemm_grid, gemm_block, 0, stream>>>(hB, W2, hA, NN);
    dots_kernel<<<wave_blocks, 256, 0, stream>>>(hA, a2, ssrc, sdst);
    edgew_kernel<<<edge_blocks, 256, 0, stream>>>(sd_pairs, ssrc, sdst, w_pairs);
    agg_kernel<true><<<wave_blocks, 256, 0, stream>>>(hA, row_ptr, w_pairs, out);
}

// Round 5
// 359.654 us; speedup vs baseline: 1.1922x; 1.1922x over previous
//
#include <hip/hip_runtime.h>
#include <hip/hip_bf16.h>

#define NN 100000
#define NE 800000
#define DIM 96
#define NEG_SLOPE 0.01f
#define SCAN_BLOCKS ((NN + 255) / 256)   // 391

typedef short bf16x8 __attribute__((ext_vector_type(8)));
typedef float f32x4  __attribute__((ext_vector_type(4)));

__device__ __forceinline__ unsigned short f32_to_bf16_rne(float f) {
    unsigned int u = __float_as_uint(f);
    unsigned int r = (u + 0x7FFFu + ((u >> 16) & 1u)) >> 16;
    return (unsigned short)r;
}

// ---------------- CSR build ----------------

__global__ __launch_bounds__(256) void hist_kernel(const int* __restrict__ src, int* __restrict__ deg) {
    int e = blockIdx.x * 256 + threadIdx.x;
    if (e < NE) atomicAdd(&deg[src[e]], 1);
}

__global__ __launch_bounds__(256) void partial_kernel(const int* __restrict__ deg, int* __restrict__ blocksum) {
    __shared__ int lds[4];
    int idx = blockIdx.x * 256 + threadIdx.x;
    int v = (idx < NN) ? deg[idx] : 0;
    for (int off = 32; off > 0; off >>= 1) v += __shfl_down(v, off);
    int wave = threadIdx.x >> 6;
    int lane = threadIdx.x & 63;
    if (lane == 0) lds[wave] = v;
    __syncthreads();
    if (threadIdx.x == 0) blocksum[blockIdx.x] = lds[0] + lds[1] + lds[2] + lds[3];
}

__global__ __launch_bounds__(512) void scan_partials_kernel(const int* __restrict__ blocksum, int* __restrict__ blockoff) {
    __shared__ int lds[512];
    int i = threadIdx.x;
    int v = (i < SCAN_BLOCKS) ? blocksum[i] : 0;
    lds[i] = v;
    __syncthreads();
    for (int off = 1; off < 512; off <<= 1) {
        int t = (i >= off) ? lds[i - off] : 0;
        __syncthreads();
        lds[i] += t;
        __syncthreads();
    }
    if (i < SCAN_BLOCKS) blockoff[i] = lds[i] - v;
}

__global__ __launch_bounds__(256) void rowptr_kernel(const int* __restrict__ deg, const int* __restrict__ blockoff,
                                                     int* __restrict__ row_ptr, int* __restrict__ cursor) {
    __shared__ int lds[256];
    int i = threadIdx.x;
    int idx = blockIdx.x * 256 + i;
    int v = (idx < NN) ? deg[idx] : 0;
    lds[i] = v;
    __syncthreads();
    for (int off = 1; off < 256; off <<= 1) {
        int t = (i >= off) ? lds[i - off] : 0;
        __syncthreads();
        lds[i] += t;
        __syncthreads();
    }
    if (idx < NN) {
        int r = blockoff[blockIdx.x] + lds[i] - v;
        row_ptr[idx] = r;
        cursor[idx]  = r;
    }
    if (idx == 0) row_ptr[NN] = NE;
}

__global__ __launch_bounds__(256) void fill_kernel(const int* __restrict__ src, const int* __restrict__ dst,
                                                   int* __restrict__ cursor, int2* __restrict__ sd_pairs) {
    int e = blockIdx.x * 256 + threadIdx.x;
    if (e < NE) {
        int s = src[e];
        int pos = atomicAdd(&cursor[s], 1);
        sd_pairs[pos] = make_int2(s, dst[e]);
    }
}

// ---------------- W convert: fp32 [k][n] -> bf16 transposed [n][k] ----------------

__global__ __launch_bounds__(256) void convw_kernel(const float* __restrict__ W, unsigned short* __restrict__ Wt) {
    int idx = blockIdx.x * 256 + threadIdx.x;   // 9216 elements
    if (idx < DIM * DIM) {
        int n = idx / DIM, k = idx % DIM;
        Wt[n * DIM + k] = f32_to_bf16_rne(W[k * DIM + n]);
    }
}

// ---------------- MFMA GEMM: C[N,96] = A[N,96] @ W[96,96] (bf16 inputs, fp32 acc) ----------------
// 256 threads = 4 waves; wave handles 16 rows x 96 cols = 6 n-tiles x 3 k-chunks = 18 MFMA.
// No LDS. B-frags register-cached from Wt (bf16 [n][k], L2-broadcast). A loaded fp32,
// converted inline to bf16 (saves a separate convert pass over 38 MB).
// 16x16x32 layouts: A lane holds A[m=lane&15][k=quad*8+j]; B lane holds B[k=quad*8+j][n=lane&15];
// C/D: col=lane&15, row=quad*4+reg.

__global__ __launch_bounds__(256) void gemm_mfma_kernel(const float* __restrict__ A,
                                                        const unsigned short* __restrict__ Wt,
                                                        float* __restrict__ C, int n) {
    const int wave = threadIdx.x >> 6;
    const int lane = threadIdx.x & 63;
    const int quad = lane >> 4;        // 0..3
    const int l16  = lane & 15;
    const int R0   = blockIdx.x * 64 + wave * 16;

    // B fragments: bfr[nt][kc]
    bf16x8 bfr[6][3];
#pragma unroll
    for (int nt = 0; nt < 6; nt++) {
        const unsigned short* wrow = Wt + (size_t)(nt * 16 + l16) * DIM;
#pragma unroll
        for (int kc = 0; kc < 3; kc++) {
            bfr[nt][kc] = *(const bf16x8*)(wrow + kc * 32 + quad * 8);
        }
    }

    // A fragments (fp32 load + inline bf16 convert)
    int arow = R0 + l16;
    if (arow >= n) arow = n - 1;                 // clamp; stores are guarded
    const float* ap = A + (size_t)arow * DIM;
    bf16x8 afr[3];
#pragma unroll
    for (int kc = 0; kc < 3; kc++) {
        float4 lo = *(const float4*)(ap + kc * 32 + quad * 8);
        float4 hi = *(const float4*)(ap + kc * 32 + quad * 8 + 4);
        union { bf16x8 v; unsigned short u[8]; } t;
        t.u[0] = f32_to_bf16_rne(lo.x); t.u[1] = f32_to_bf16_rne(lo.y);
        t.u[2] = f32_to_bf16_rne(lo.z); t.u[3] = f32_to_bf16_rne(lo.w);
        t.u[4] = f32_to_bf16_rne(hi.x); t.u[5] = f32_to_bf16_rne(hi.y);
        t.u[6] = f32_to_bf16_rne(hi.z); t.u[7] = f32_to_bf16_rne(hi.w);
        afr[kc] = t.v;
    }

    f32x4 acc[6];
#pragma unroll
    for (int nt = 0; nt < 6; nt++) acc[nt] = (f32x4){0.f, 0.f, 0.f, 0.f};

#pragma unroll
    for (int kc = 0; kc < 3; kc++) {
#pragma unroll
        for (int nt = 0; nt < 6; nt++) {
            acc[nt] = __builtin_amdgcn_mfma_f32_16x16x32_bf16(afr[kc], bfr[nt][kc], acc[nt], 0, 0, 0);
        }
    }

    // store: row = R0 + quad*4 + r, col = nt*16 + l16
#pragma unroll
    for (int r = 0; r < 4; r++) {
        int orow = R0 + quad * 4 + r;
        if (orow < n) {
            float* crow = C + (size_t)orow * DIM;
#pragma unroll
            for (int nt = 0; nt < 6; nt++) crow[nt * 16 + l16] = acc[nt][r];
        }
    }
}

// ---------------- per-node attention dots ----------------

__global__ __launch_bounds__(256) void dots_kernel(const float* __restrict__ h, const float* __restrict__ a,
                                                   float* __restrict__ ssrc, float* __restrict__ sdst) {
    int gid  = blockIdx.x * 256 + threadIdx.x;
    int node = gid >> 6;
    int lane = threadIdx.x & 63;
    if (node >= NN) return;
    const float* hr = h + (size_t)node * DIM;
    float v0 = hr[lane];
    float v1 = (lane < 32) ? hr[64 + lane] : 0.f;
    float a0 = a[lane];
    float a1v = (lane < 32) ? a[64 + lane] : 0.f;
    float b0 = a[96 + lane];
    float b1 = (lane < 32) ? a[160 + lane] : 0.f;
    float ps = v0 * a0 + v1 * a1v;
    float pd = v0 * b0 + v1 * b1;
    for (int off = 32; off > 0; off >>= 1) {
        ps += __shfl_down(ps, off);
        pd += __shfl_down(pd, off);
    }
    if (lane == 0) {
        ssrc[node] = ps;
        sdst[node] = pd;
    }
}

// ---------------- edge weights (edge-parallel, permuted order) ----------------

__global__ __launch_bounds__(256) void edgew_kernel(const int2* __restrict__ sd_pairs,
                                                    const float* __restrict__ ssrc, const float* __restrict__ sdst,
                                                    int2* __restrict__ w_pairs) {
    int p = blockIdx.x * 256 + threadIdx.x;
    if (p >= NE) return;
    int2 sd = sd_pairs[p];
    float s  = ssrc[sd.x] + sdst[sd.y];
    float lr = s > 0.f ? s : NEG_SLOPE * s;
    float w  = __expf(-lr);
    w_pairs[p] = make_int2(sd.y, __float_as_int(w));
}

// ---------------- CSR aggregation ----------------

template <bool RELU>
__global__ __launch_bounds__(256) void agg_kernel(const float* __restrict__ h,
                                                  const int* __restrict__ row_ptr,
                                                  const int2* __restrict__ w_pairs,
                                                  float* __restrict__ out) {
    int gid  = blockIdx.x * 256 + threadIdx.x;
    int node = gid >> 6;
    int lane = threadIdx.x & 63;
    if (node >= NN) return;
    int start = row_ptr[node];
    int end   = row_ptr[node + 1];
    float acc0 = 0.f, acc1 = 0.f, wsum = 0.f;

    int p = start;
    for (; p + 4 <= end; p += 4) {
        int2 q0 = w_pairs[p + 0];
        int2 q1 = w_pairs[p + 1];
        int2 q2 = w_pairs[p + 2];
        int2 q3 = w_pairs[p + 3];
        const float* h0 = h + (size_t)q0.x * DIM;
        const float* h1 = h + (size_t)q1.x * DIM;
        const float* h2 = h + (size_t)q2.x * DIM;
        const float* h3 = h + (size_t)q3.x * DIM;
        float w0 = __int_as_float(q0.y), w1 = __int_as_float(q1.y);
        float w2 = __int_as_float(q2.y), w3 = __int_as_float(q3.y);
        float x0 = h0[lane], x1 = h1[lane], x2 = h2[lane], x3 = h3[lane];
        float y0 = 0.f, y1 = 0.f, y2 = 0.f, y3 = 0.f;
        if (lane < 32) {
            y0 = h0[64 + lane]; y1 = h1[64 + lane]; y2 = h2[64 + lane]; y3 = h3[64 + lane];
        }
        acc0 = fmaf(w0, x0, fmaf(w1, x1, fmaf(w2, x2, fmaf(w3, x3, acc0))));
        acc1 = fmaf(w0, y0, fmaf(w1, y1, fmaf(w2, y2, fmaf(w3, y3, acc1))));
        wsum += (w0 + w1) + (w2 + w3);
    }
    for (; p < end; p++) {
        int2 q = w_pairs[p];
        const float* hr = h + (size_t)q.x * DIM;
        float w = __int_as_float(q.y);
        wsum += w;
        acc0 = fmaf(w, hr[lane], acc0);
        if (lane < 32) acc1 = fmaf(w, hr[64 + lane], acc1);
    }

    float inv = 1.f / wsum;
    float r0 = acc0 * inv;
    float r1 = acc1 * inv;
    if (RELU) {
        r0 = fmaxf(r0, 0.f);
        r1 = fmaxf(r1, 0.f);
    }
    float* orow = out + (size_t)node * DIM;
    orow[lane] = r0;
    if (lane < 32) orow[64 + lane] = r1;
}

// ---------------- launch ----------------

extern "C" void kernel_launch(void* const* d_in, const int* in_sizes, int n_in,
                              void* d_out, int out_size, void* d_ws, size_t ws_size,
                              hipStream_t stream) {
    (void)in_sizes; (void)n_in; (void)out_size; (void)ws_size;
    const int*   edge_index = (const int*)d_in[0];
    const float* x  = (const float*)d_in[1];
    const float* W1 = (const float*)d_in[2];
    const float* a1 = (const float*)d_in[3];
    const float* W2 = (const float*)d_in[4];
    const float* a2 = (const float*)d_in[5];
    float* out = (float*)d_out;

    const int* src = edge_index;
    const int* dst = edge_index + NE;

    char* ws = (char*)d_ws;
    size_t off = 0;
    auto alloc = [&](size_t bytes) -> void* {
        void* p = ws + off;
        off += (bytes + 255) & ~(size_t)255;
        return p;
    };
    float* hA        = (float*)alloc((size_t)NN * DIM * 4);
    float* hB        = (float*)alloc((size_t)NN * DIM * 4);
    float* ssrc      = (float*)alloc((size_t)NN * 4);
    float* sdst      = (float*)alloc((size_t)NN * 4);
    int*   deg       = (int*)alloc((size_t)NN * 4);
    int*   row_ptr   = (int*)alloc((size_t)(NN + 1) * 4);
    int*   cursor    = (int*)alloc((size_t)NN * 4);
    int2*  sd_pairs  = (int2*)alloc((size_t)NE * 8);
    int2*  w_pairs   = (int2*)alloc((size_t)NE * 8);
    int*   blocksum  = (int*)alloc((size_t)SCAN_BLOCKS * 4);
    int*   blockoff  = (int*)alloc((size_t)SCAN_BLOCKS * 4);
    unsigned short* Wt1 = (unsigned short*)alloc((size_t)DIM * DIM * 2);
    unsigned short* Wt2 = (unsigned short*)alloc((size_t)DIM * DIM * 2);

    // ---- build CSR + W converts ----
    hipMemsetAsync(deg, 0, (size_t)NN * 4, stream);
    hist_kernel<<<(NE + 255) / 256, 256, 0, stream>>>(src, deg);
    partial_kernel<<<SCAN_BLOCKS, 256, 0, stream>>>(deg, blocksum);
    scan_partials_kernel<<<1, 512, 0, stream>>>(blocksum, blockoff);
    rowptr_kernel<<<SCAN_BLOCKS, 256, 0, stream>>>(deg, blockoff, row_ptr, cursor);
    fill_kernel<<<(NE + 255) / 256, 256, 0, stream>>>(src, dst, cursor, sd_pairs);
    convw_kernel<<<(DIM * DIM + 255) / 256, 256, 0, stream>>>(W1, Wt1);
    convw_kernel<<<(DIM * DIM + 255) / 256, 256, 0, stream>>>(W2, Wt2);

    int gemm_grid   = (NN + 63) / 64;                 // 1563 (64 rows/block)
    int wave_blocks = ((NN * 64) + 255) / 256;        // 25000
    int edge_blocks = (NE + 255) / 256;               // 3125

    // ---- layer 1 ----
    gemm_mfma_kernel<<<gemm_grid, 256, 0, stream>>>(x, Wt1, hA, NN);
    dots_kernel<<<wave_blocks, 256, 0, stream>>>(hA, a1, ssrc, sdst);
    edgew_kernel<<<edge_blocks, 256, 0, stream>>>(sd_pairs, ssrc, sdst, w_pairs);
    agg_kernel<false><<<wave_blocks, 256, 0, stream>>>(hA, row_ptr, w_pairs, hB);

    // ---- layer 2 ----
    gemm_mfma_kernel<<<gemm_grid, 256, 0, stream>>>(hB, Wt2, hA, NN);
    dots_kernel<<<wave_blocks, 256, 0, stream>>>(hA, a2, ssrc, sdst);
    edgew_kernel<<<edge_blocks, 256, 0, stream>>>(sd_pairs, ssrc, sdst, w_pairs);
    agg_kernel<true><<<wave_blocks, 256, 0, stream>>>(hA, row_ptr, w_pairs, out);
}

// Round 6
// 329.164 us; speedup vs baseline: 1.3026x; 1.0926x over previous
//
#include <hip/hip_runtime.h>
#include <hip/hip_bf16.h>

#define NN 100000
#define NE 800000
#define DIM 96
#define NEG_SLOPE 0.01f
#define SCAN_BLOCKS ((NN + 255) / 256)   // 391

typedef short bf16x8 __attribute__((ext_vector_type(8)));
typedef float f32x4  __attribute__((ext_vector_type(4)));

__device__ __forceinline__ unsigned short f32_to_bf16_rne(float f) {
    unsigned int u = __float_as_uint(f);
    unsigned int r = (u + 0x7FFFu + ((u >> 16) & 1u)) >> 16;
    return (unsigned short)r;
}
__device__ __forceinline__ float bf16lo_to_f32(unsigned int u) {   // low ushort
    return __uint_as_float(u << 16);
}
__device__ __forceinline__ float bf16hi_to_f32(unsigned int u) {   // high ushort
    return __uint_as_float(u & 0xFFFF0000u);
}

// ---------------- CSR build ----------------

__global__ __launch_bounds__(256) void hist_kernel(const int* __restrict__ src, int* __restrict__ deg) {
    int e = blockIdx.x * 256 + threadIdx.x;
    if (e < NE) atomicAdd(&deg[src[e]], 1);
}

__global__ __launch_bounds__(256) void partial_kernel(const int* __restrict__ deg, int* __restrict__ blocksum) {
    __shared__ int lds[4];
    int idx = blockIdx.x * 256 + threadIdx.x;
    int v = (idx < NN) ? deg[idx] : 0;
    for (int off = 32; off > 0; off >>= 1) v += __shfl_down(v, off);
    int wave = threadIdx.x >> 6;
    int lane = threadIdx.x & 63;
    if (lane == 0) lds[wave] = v;
    __syncthreads();
    if (threadIdx.x == 0) blocksum[blockIdx.x] = lds[0] + lds[1] + lds[2] + lds[3];
}

__global__ __launch_bounds__(512) void scan_partials_kernel(const int* __restrict__ blocksum, int* __restrict__ blockoff) {
    __shared__ int lds[512];
    int i = threadIdx.x;
    int v = (i < SCAN_BLOCKS) ? blocksum[i] : 0;
    lds[i] = v;
    __syncthreads();
    for (int off = 1; off < 512; off <<= 1) {
        int t = (i >= off) ? lds[i - off] : 0;
        __syncthreads();
        lds[i] += t;
        __syncthreads();
    }
    if (i < SCAN_BLOCKS) blockoff[i] = lds[i] - v;
}

__global__ __launch_bounds__(256) void rowptr_kernel(const int* __restrict__ deg, const int* __restrict__ blockoff,
                                                     int* __restrict__ row_ptr, int* __restrict__ cursor) {
    __shared__ int lds[256];
    int i = threadIdx.x;
    int idx = blockIdx.x * 256 + i;
    int v = (idx < NN) ? deg[idx] : 0;
    lds[i] = v;
    __syncthreads();
    for (int off = 1; off < 256; off <<= 1) {
        int t = (i >= off) ? lds[i - off] : 0;
        __syncthreads();
        lds[i] += t;
        __syncthreads();
    }
    if (idx < NN) {
        int r = blockoff[blockIdx.x] + lds[i] - v;
        row_ptr[idx] = r;
        cursor[idx]  = r;
    }
    if (idx == 0) row_ptr[NN] = NE;
}

__global__ __launch_bounds__(256) void fill_kernel(const int* __restrict__ src, const int* __restrict__ dst,
                                                   int* __restrict__ cursor, int2* __restrict__ sd_pairs) {
    int e = blockIdx.x * 256 + threadIdx.x;
    if (e < NE) {
        int s = src[e];
        int pos = atomicAdd(&cursor[s], 1);
        sd_pairs[pos] = make_int2(s, dst[e]);
    }
}

// ---------------- W convert: both weights fp32 [k][n] -> bf16 transposed [n][k] ----------------

__global__ __launch_bounds__(256) void convw_kernel(const float* __restrict__ W1, unsigned short* __restrict__ Wt1,
                                                    const float* __restrict__ W2, unsigned short* __restrict__ Wt2) {
    int idx = blockIdx.x * 256 + threadIdx.x;   // 2*9216
    if (idx < DIM * DIM) {
        int n = idx / DIM, k = idx % DIM;
        Wt1[n * DIM + k] = f32_to_bf16_rne(W1[k * DIM + n]);
    } else if (idx < 2 * DIM * DIM) {
        int j = idx - DIM * DIM;
        int n = j / DIM, k = j % DIM;
        Wt2[n * DIM + k] = f32_to_bf16_rne(W2[k * DIM + n]);
    }
}

// ---------------- MFMA GEMM + fused dots ----------------
// H[N,96](bf16) = A[N,96] @ W[96,96]; ssrc[n]=H[n]·a[:96], sdst[n]=H[n]·a[96:] (fp32, pre-rounding).
// 256 threads = 4 waves; wave: 16 rows x 96 cols = 6 n-tiles x 3 k-chunks MFMA 16x16x32.
// No LDS; B-frags register-cached from Wt (bf16 [n][k], L2-broadcast).
// C/D layout: col=lane&15, row=quad*4+reg. Each quad's 16 lanes hold 4 full rows.

template <bool A_BF16>
__global__ __launch_bounds__(256) void gemm_mfma_kernel(const void* __restrict__ A_,
                                                        const unsigned short* __restrict__ Wt,
                                                        const float* __restrict__ avec,
                                                        unsigned short* __restrict__ Hout,
                                                        float* __restrict__ ssrc, float* __restrict__ sdst,
                                                        int n) {
    const int wave = threadIdx.x >> 6;
    const int lane = threadIdx.x & 63;
    const int quad = lane >> 4;        // 0..3
    const int l16  = lane & 15;
    const int R0   = blockIdx.x * 64 + wave * 16;

    // B fragments
    bf16x8 bfr[6][3];
#pragma unroll
    for (int nt = 0; nt < 6; nt++) {
        const unsigned short* wrow = Wt + (size_t)(nt * 16 + l16) * DIM;
#pragma unroll
        for (int kc = 0; kc < 3; kc++) bfr[nt][kc] = *(const bf16x8*)(wrow + kc * 32 + quad * 8);
    }

    // A fragments
    int arow = R0 + l16;
    if (arow >= n) arow = n - 1;                 // clamp; stores guarded
    bf16x8 afr[3];
    if (A_BF16) {
        const unsigned short* ap = (const unsigned short*)A_ + (size_t)arow * DIM;
#pragma unroll
        for (int kc = 0; kc < 3; kc++) afr[kc] = *(const bf16x8*)(ap + kc * 32 + quad * 8);
    } else {
        const float* ap = (const float*)A_ + (size_t)arow * DIM;
#pragma unroll
        for (int kc = 0; kc < 3; kc++) {
            float4 lo = *(const float4*)(ap + kc * 32 + quad * 8);
            float4 hi = *(const float4*)(ap + kc * 32 + quad * 8 + 4);
            union { bf16x8 v; unsigned short u[8]; } t;
            t.u[0] = f32_to_bf16_rne(lo.x); t.u[1] = f32_to_bf16_rne(lo.y);
            t.u[2] = f32_to_bf16_rne(lo.z); t.u[3] = f32_to_bf16_rne(lo.w);
            t.u[4] = f32_to_bf16_rne(hi.x); t.u[5] = f32_to_bf16_rne(hi.y);
            t.u[6] = f32_to_bf16_rne(hi.z); t.u[7] = f32_to_bf16_rne(hi.w);
            afr[kc] = t.v;
        }
    }

    f32x4 acc[6];
#pragma unroll
    for (int nt = 0; nt < 6; nt++) acc[nt] = (f32x4){0.f, 0.f, 0.f, 0.f};
#pragma unroll
    for (int kc = 0; kc < 3; kc++)
#pragma unroll
        for (int nt = 0; nt < 6; nt++)
            acc[nt] = __builtin_amdgcn_mfma_f32_16x16x32_bf16(afr[kc], bfr[nt][kc], acc[nt], 0, 0, 0);

    // ---- fused dots: ps[r] = sum_c C[row][c]*a[c], pd[r] with a[96+c] ----
    float as_[6], ad_[6];
#pragma unroll
    for (int nt = 0; nt < 6; nt++) {
        as_[nt] = avec[nt * 16 + l16];
        ad_[nt] = avec[96 + nt * 16 + l16];
    }
    float ps[4], pd[4];
#pragma unroll
    for (int r = 0; r < 4; r++) {
        float s = 0.f, d = 0.f;
#pragma unroll
        for (int nt = 0; nt < 6; nt++) {
            s = fmaf(acc[nt][r], as_[nt], s);
            d = fmaf(acc[nt][r], ad_[nt], d);
        }
        ps[r] = s; pd[r] = d;
    }
#pragma unroll
    for (int m = 1; m < 16; m <<= 1) {
#pragma unroll
        for (int r = 0; r < 4; r++) {
            ps[r] += __shfl_xor(ps[r], m);
            pd[r] += __shfl_xor(pd[r], m);
        }
    }
    {
        float psel = (l16 == 0) ? ps[0] : (l16 == 1) ? ps[1] : (l16 == 2) ? ps[2] : ps[3];
        float dsel = (l16 == 8) ? pd[0] : (l16 == 9) ? pd[1] : (l16 == 10) ? pd[2] : pd[3];
        int rs = R0 + quad * 4 + l16;
        int rd = R0 + quad * 4 + (l16 - 8);
        if (l16 < 4 && rs < n) ssrc[rs] = psel;
        if (l16 >= 8 && l16 < 12 && rd < n) sdst[rd] = dsel;
    }

    // ---- store H as bf16: row = R0+quad*4+r, col = nt*16+l16 ----
#pragma unroll
    for (int r = 0; r < 4; r++) {
        int orow = R0 + quad * 4 + r;
        if (orow < n) {
            unsigned short* hrow = Hout + (size_t)orow * DIM;
#pragma unroll
            for (int nt = 0; nt < 6; nt++) hrow[nt * 16 + l16] = f32_to_bf16_rne(acc[nt][r]);
        }
    }
}

// ---------------- edge weights (edge-parallel, permuted order) ----------------

__global__ __launch_bounds__(256) void edgew_kernel(const int2* __restrict__ sd_pairs,
                                                    const float* __restrict__ ssrc, const float* __restrict__ sdst,
                                                    int2* __restrict__ w_pairs) {
    int p = blockIdx.x * 256 + threadIdx.x;
    if (p >= NE) return;
    int2 sd = sd_pairs[p];
    float s  = ssrc[sd.x] + sdst[sd.y];
    float lr = s > 0.f ? s : NEG_SLOPE * s;
    float w  = __expf(-lr);
    w_pairs[p] = make_int2(sd.y, __float_as_int(w));
}

// ---------------- CSR aggregation (bf16 h gather) ----------------
// one wave per node; lanes 0..47 each own one uint = 2 bf16 features.

template <bool RELU, bool OUT_BF16>
__global__ __launch_bounds__(256) void agg_kernel(const unsigned short* __restrict__ h,
                                                  const int* __restrict__ row_ptr,
                                                  const int2* __restrict__ w_pairs,
                                                  void* __restrict__ out) {
    int gid  = blockIdx.x * 256 + threadIdx.x;
    int node = gid >> 6;
    int lane = threadIdx.x & 63;
    if (node >= NN) return;
    int start = row_ptr[node];
    int end   = row_ptr[node + 1];
    const bool act = lane < 48;
    float acc0 = 0.f, acc1 = 0.f, wsum = 0.f;

    int p = start;
    for (; p + 8 <= end; p += 8) {
        int2 q[8];
#pragma unroll
        for (int i = 0; i < 8; i++) q[i] = w_pairs[p + i];
        unsigned int u[8];
        if (act) {
#pragma unroll
            for (int i = 0; i < 8; i++)
                u[i] = ((const unsigned int*)(h + (size_t)q[i].x * DIM))[lane];
        }
#pragma unroll
        for (int i = 0; i < 8; i++) {
            float w = __int_as_float(q[i].y);
            wsum += w;
            if (act) {
                acc0 = fmaf(w, bf16lo_to_f32(u[i]), acc0);
                acc1 = fmaf(w, bf16hi_to_f32(u[i]), acc1);
            }
        }
    }
    for (; p < end; p++) {
        int2 q = w_pairs[p];
        float w = __int_as_float(q.y);
        wsum += w;
        if (act) {
            unsigned int u = ((const unsigned int*)(h + (size_t)q.x * DIM))[lane];
            acc0 = fmaf(w, bf16lo_to_f32(u), acc0);
            acc1 = fmaf(w, bf16hi_to_f32(u), acc1);
        }
    }

    float inv = 1.f / wsum;
    float r0 = acc0 * inv;
    float r1 = acc1 * inv;
    if (RELU) { r0 = fmaxf(r0, 0.f); r1 = fmaxf(r1, 0.f); }
    if (act) {
        if (OUT_BF16) {
            unsigned int pk = (unsigned int)f32_to_bf16_rne(r0) | ((unsigned int)f32_to_bf16_rne(r1) << 16);
            ((unsigned int*)out)[(size_t)node * 48 + lane] = pk;
        } else {
            ((float2*)out)[(size_t)node * 48 + lane] = make_float2(r0, r1);
        }
    }
}

// ---------------- launch ----------------

extern "C" void kernel_launch(void* const* d_in, const int* in_sizes, int n_in,
                              void* d_out, int out_size, void* d_ws, size_t ws_size,
                              hipStream_t stream) {
    (void)in_sizes; (void)n_in; (void)out_size; (void)ws_size;
    const int*   edge_index = (const int*)d_in[0];
    const float* x  = (const float*)d_in[1];
    const float* W1 = (const float*)d_in[2];
    const float* a1 = (const float*)d_in[3];
    const float* W2 = (const float*)d_in[4];
    const float* a2 = (const float*)d_in[5];
    float* out = (float*)d_out;

    const int* src = edge_index;
    const int* dst = edge_index + NE;

    char* ws = (char*)d_ws;
    size_t off = 0;
    auto alloc = [&](size_t bytes) -> void* {
        void* p = ws + off;
        off += (bytes + 255) & ~(size_t)255;
        return p;
    };
    unsigned short* hbf   = (unsigned short*)alloc((size_t)NN * DIM * 2);  // gemm output (both layers)
    unsigned short* h2bf  = (unsigned short*)alloc((size_t)NN * DIM * 2);  // layer-1 agg output
    float* ssrc      = (float*)alloc((size_t)NN * 4);
    float* sdst      = (float*)alloc((size_t)NN * 4);
    int*   deg       = (int*)alloc((size_t)NN * 4);
    int*   row_ptr   = (int*)alloc((size_t)(NN + 1) * 4);
    int*   cursor    = (int*)alloc((size_t)NN * 4);
    int2*  sd_pairs  = (int2*)alloc((size_t)NE * 8);
    int2*  w_pairs   = (int2*)alloc((size_t)NE * 8);
    int*   blocksum  = (int*)alloc((size_t)SCAN_BLOCKS * 4);
    int*   blockoff  = (int*)alloc((size_t)SCAN_BLOCKS * 4);
    unsigned short* Wt1 = (unsigned short*)alloc((size_t)DIM * DIM * 2);
    unsigned short* Wt2 = (unsigned short*)alloc((size_t)DIM * DIM * 2);

    // ---- build CSR + W converts ----
    hipMemsetAsync(deg, 0, (size_t)NN * 4, stream);
    hist_kernel<<<(NE + 255) / 256, 256, 0, stream>>>(src, deg);
    partial_kernel<<<SCAN_BLOCKS, 256, 0, stream>>>(deg, blocksum);
    scan_partials_kernel<<<1, 512, 0, stream>>>(blocksum, blockoff);
    rowptr_kernel<<<SCAN_BLOCKS, 256, 0, stream>>>(deg, blockoff, row_ptr, cursor);
    fill_kernel<<<(NE + 255) / 256, 256, 0, stream>>>(src, dst, cursor, sd_pairs);
    convw_kernel<<<(2 * DIM * DIM + 255) / 256, 256, 0, stream>>>(W1, Wt1, W2, Wt2);

    int gemm_grid   = (NN + 63) / 64;                 // 1563 (64 rows/block)
    int wave_blocks = ((NN * 64) + 255) / 256;        // 25000
    int edge_blocks = (NE + 255) / 256;               // 3125

    // ---- layer 1 ----
    gemm_mfma_kernel<false><<<gemm_grid, 256, 0, stream>>>(x, Wt1, a1, hbf, ssrc, sdst, NN);
    edgew_kernel<<<edge_blocks, 256, 0, stream>>>(sd_pairs, ssrc, sdst, w_pairs);
    agg_kernel<false, true><<<wave_blocks, 256, 0, stream>>>(hbf, row_ptr, w_pairs, h2bf);

    // ---- layer 2 ----
    gemm_mfma_kernel<true><<<gemm_grid, 256, 0, stream>>>(h2bf, Wt2, a2, hbf, ssrc, sdst, NN);
    edgew_kernel<<<edge_blocks, 256, 0, stream>>>(sd_pairs, ssrc, sdst, w_pairs);
    agg_kernel<true, false><<<wave_blocks, 256, 0, stream>>>(hbf, row_ptr, w_pairs, out);
}